// Round 10
// baseline (181.642 us; speedup 1.0000x reference)
//
#include <hip/hip_runtime.h>
#include <hip/hip_bf16.h>
#include <stdint.h>

#define NN 4096
#define KIN 512
#define HH 8
#define HF 256
#define LOG2E 1.4426950408889634f

typedef float f32x4 __attribute__((ext_vector_type(4)));
typedef short s16x8 __attribute__((ext_vector_type(8)));
typedef short s16x2 __attribute__((ext_vector_type(2)));
typedef __bf16 bf16x8 __attribute__((ext_vector_type(8)));
typedef _Float16 h16x8 __attribute__((ext_vector_type(8)));
typedef unsigned int u32x4 __attribute__((ext_vector_type(4)));

// ---------------------------------------------------------------------------
// k_pre: fused k_pack (blocks 0..2047) + k_prep (blocks 2048..2303).
//  pack: adjacency (mode sniffed per-block) -> bitmask bm[4096][128] (2 MB)
//  prep: x = node@W via bf16 MFMA; emits XB (f16, B-fragment-major, 2 MB)
//        and f16 score tables E1=2^s, E2=2^(0.2s), F1=2^t, F2=2^(0.2t).
// ---------------------------------------------------------------------------
__global__ __launch_bounds__(256) void k_pre(
    const void* __restrict__ adjv, const float* __restrict__ node,
    const float* __restrict__ Wm, const float* __restrict__ avec,
    uint32_t* __restrict__ bm, _Float16* __restrict__ XB,
    _Float16* __restrict__ srcE1, _Float16* __restrict__ srcE2,
    _Float16* __restrict__ tgtF1, _Float16* __restrict__ tgtF2) {
  __shared__ __bf16 Ald[64][40];
  __shared__ __bf16 Bld[64][40];
  __shared__ _Float16 Cs[64][72];
  const int tid = threadIdx.x;

  if (blockIdx.x < 2048) {
    // ---------------- pack path ----------------
    __shared__ int smode;
    if (tid == 0) {
      const uint32_t* aw = (const uint32_t*)adjv;
      const uint32_t w0 = aw[0];
      int f;
      if (w0 == 0x3F800000u) f = 2;               // fp32 0/1
      else if ((w0 & 0xFFFFu) == 0x3F80u) f = 3;  // bf16 0/1
      else {
        int alli = 1;
        for (int k = 0; k < 64; ++k)
          if (aw[k] > 1u) { alli = 0; break; }
        f = alli ? 1 : 0;                         // int32 : uint8
      }
      smode = f;
    }
    __syncthreads();
    const int mode = smode;
    const int t = blockIdx.x * 256 + tid;         // 0..524287
    const int r = t >> 7, w = t & 127;
    uint32_t word = 0;
    if (mode == 0) {
      const u32x4* p = (const u32x4*)((const uint8_t*)adjv + ((size_t)r << 12) + w * 32);
#pragma unroll
      for (int k = 0; k < 2; ++k) {
        const u32x4 v = __builtin_nontemporal_load(&p[k]);
#pragma unroll
        for (int q = 0; q < 4; ++q)
#pragma unroll
          for (int b = 0; b < 4; ++b)
            if ((v[q] >> (8 * b)) & 0xFFu) word |= (1u << (k * 16 + q * 4 + b));
      }
    } else if (mode == 3) {
      const u32x4* p = (const u32x4*)((const uint16_t*)adjv + ((size_t)r << 12) + w * 32);
#pragma unroll
      for (int k = 0; k < 4; ++k) {
        const u32x4 v = __builtin_nontemporal_load(&p[k]);
#pragma unroll
        for (int q = 0; q < 4; ++q) {
          if (v[q] & 0xFFFFu) word |= (1u << (k * 8 + q * 2 + 0));
          if (v[q] >> 16)     word |= (1u << (k * 8 + q * 2 + 1));
        }
      }
    } else {
      const u32x4* p = (const u32x4*)((const uint32_t*)adjv + ((size_t)r << 12) + w * 32);
#pragma unroll
      for (int k = 0; k < 8; ++k) {
        const u32x4 v = __builtin_nontemporal_load(&p[k]);
#pragma unroll
        for (int q = 0; q < 4; ++q)
          if (v[q]) word |= (1u << (k * 4 + q));
      }
    }
    bm[t] = word;
    return;
  }

  // ---------------- prep path ----------------
  const int pb = blockIdx.x - 2048;               // 0..255
  const int bx = pb & 63, by = pb >> 6;
  const int wv = tid >> 6, ln = tid & 63, nl = ln & 15, qd = ln >> 4;
  const int row0 = bx * 64, col0 = by * 64;
  const int rA = tid >> 2, kA = (tid & 3) * 8;
  const int kB = tid >> 3, cB = (tid & 7) * 8;

  f32x4 acc[4] = {{0,0,0,0},{0,0,0,0},{0,0,0,0},{0,0,0,0}};
  float4 a0, a1, b0, b1;

  auto ldg = [&](int k0) {
    a0 = *(const float4*)(node + (size_t)(row0 + rA) * KIN + k0 + kA);
    a1 = *(const float4*)(node + (size_t)(row0 + rA) * KIN + k0 + kA + 4);
    b0 = *(const float4*)(Wm + (size_t)(k0 + kB) * HF + col0 + cB);
    b1 = *(const float4*)(Wm + (size_t)(k0 + kB) * HF + col0 + cB + 4);
  };

  ldg(0);
  for (int k0 = 0; k0 < KIN; k0 += 32) {
    __syncthreads();
    {
      union { bf16x8 v; s16x8 s; } pk;
      pk.v[0] = (__bf16)a0.x; pk.v[1] = (__bf16)a0.y;
      pk.v[2] = (__bf16)a0.z; pk.v[3] = (__bf16)a0.w;
      pk.v[4] = (__bf16)a1.x; pk.v[5] = (__bf16)a1.y;
      pk.v[6] = (__bf16)a1.z; pk.v[7] = (__bf16)a1.w;
      *(s16x8*)&Ald[rA][kA] = pk.s;
      Bld[cB + 0][kB] = (__bf16)b0.x;
      Bld[cB + 1][kB] = (__bf16)b0.y;
      Bld[cB + 2][kB] = (__bf16)b0.z;
      Bld[cB + 3][kB] = (__bf16)b0.w;
      Bld[cB + 4][kB] = (__bf16)b1.x;
      Bld[cB + 5][kB] = (__bf16)b1.y;
      Bld[cB + 6][kB] = (__bf16)b1.z;
      Bld[cB + 7][kB] = (__bf16)b1.w;
    }
    __syncthreads();
    if (k0 + 32 < KIN) ldg(k0 + 32);
    const s16x8 af = *(const s16x8*)&Ald[wv * 16 + nl][qd * 8];
#pragma unroll
    for (int ct = 0; ct < 4; ++ct) {
      const s16x8 bfr = *(const s16x8*)&Bld[ct * 16 + nl][qd * 8];
      acc[ct] = __builtin_amdgcn_mfma_f32_16x16x32_bf16(af, bfr, acc[ct], 0, 0, 0);
    }
  }

  // stage C-tile in LDS [col][row] as f16
#pragma unroll
  for (int ct = 0; ct < 4; ++ct)
#pragma unroll
    for (int r = 0; r < 4; ++r)
      Cs[ct * 16 + nl][wv * 16 + qd * 4 + r] = (_Float16)acc[ct][r];
  __syncthreads();
  // write XB: 8 combos (hp, jcl, half) x 64 lanes, 16B each, coalesced
  {
    const int l = tid & 63;
#pragma unroll
    for (int i = 0; i < 2; ++i) {
      const int cmb = i * 4 + (tid >> 6);
      const int hp = cmb >> 2, jcl = (cmb >> 1) & 1, half = cmb & 1;
      const int cp = hp * 32 + half * 16 + (l & 15);
      const int rp = jcl * 32 + (l >> 4) * 8;
      const int hg = by * 2 + hp;
      const int jc = bx * 2 + jcl;
      *(h16x8*)(XB + (((size_t)(hg * 128 + jc)) * 2 + half) * 512 + l * 8) =
          *(const h16x8*)&Cs[cp][rp];
    }
  }

  const float as0 = avec[nl] * LOG2E, as1 = avec[16 + nl] * LOG2E;
  const float at0 = avec[32 + nl] * LOG2E, at1 = avec[48 + nl] * LOG2E;
#pragma unroll
  for (int hp = 0; hp < 2; ++hp) {
    float ps[4], pt[4];
#pragma unroll
    for (int r = 0; r < 4; ++r) {
      ps[r] = acc[2 * hp][r] * as0 + acc[2 * hp + 1][r] * as1;
      pt[r] = acc[2 * hp][r] * at0 + acc[2 * hp + 1][r] * at1;
    }
#pragma unroll
    for (int m = 1; m <= 8; m <<= 1)
#pragma unroll
      for (int r = 0; r < 4; ++r) {
        ps[r] += __shfl_xor(ps[r], m);
        pt[r] += __shfl_xor(pt[r], m);
      }
    if (nl == 0) {
      const int h = by * 2 + hp;
#pragma unroll
      for (int r = 0; r < 4; ++r) {
        const int idx = h * NN + row0 + wv * 16 + qd * 4 + r;
        srcE1[idx] = (_Float16)exp2f(ps[r]);
        srcE2[idx] = (_Float16)exp2f(0.2f * ps[r]);
        tgtF1[idx] = (_Float16)exp2f(pt[r]);
        tgtF2[idx] = (_Float16)exp2f(0.2f * pt[r]);
      }
    }
  }
}

// ---------------------------------------------------------------------------
// k_attn: block = (16-row tile, head), 4 waves each owning a 1024-j slice.
// No transcendentals: p = adj & (a>=1 ? a : b), a=F1*E1, b=F2*E2 (packed
// f16 muls; branch select via integer compare on positive-f16 bit patterns).
// f16 MFMA (f32 accum); den via ones-MFMA; cross-wave LDS reduction.
// ---------------------------------------------------------------------------
__global__ __launch_bounds__(256, 8) void k_attn(
    const uint32_t* __restrict__ bm, const _Float16* __restrict__ XB,
    const _Float16* __restrict__ srcE1, const _Float16* __restrict__ srcE2,
    const _Float16* __restrict__ tgtF1, const _Float16* __restrict__ tgtF2,
    float* __restrict__ out) {
  __shared__ float Red[3][64][13];
  const int tid = threadIdx.x;
  const int wv = tid >> 6, ln = tid & 63, nl = ln & 15, qd = ln >> 4;
  const int tile = blockIdx.x >> 3;          // 0..255
  const int h = blockIdx.x & 7;
  const int i0 = tile * 16;
  const int j0 = wv * 1024;

  const _Float16 f1 = tgtF1[h * NN + i0 + nl];
  const _Float16 f2 = tgtF2[h * NN + i0 + nl];
  const h16x8 F1 = {f1, f1, f1, f1, f1, f1, f1, f1};
  const h16x8 F2 = {f2, f2, f2, f2, f2, f2, f2, f2};
  const h16x8 ONES = {(_Float16)1.0f, (_Float16)1.0f, (_Float16)1.0f,
                      (_Float16)1.0f, (_Float16)1.0f, (_Float16)1.0f,
                      (_Float16)1.0f, (_Float16)1.0f};
  const _Float16* E1 = srcE1 + h * NN;
  const _Float16* E2 = srcE2 + h * NN;
  const _Float16* xb = XB + ((size_t)h << 17) + ln * 8;
  const uint32_t* rowbm = bm + (size_t)(i0 + nl) * 128;

  f32x4 acc0 = {0,0,0,0}, acc1 = {0,0,0,0}, accD = {0,0,0,0};

  u32x4 bits = *(const u32x4*)(rowbm + (j0 >> 5));
  for (int c = 0; c < 8; ++c) {
    const int jb = j0 + c * 128;
    u32x4 nbits;
    if (c + 1 < 8) nbits = *(const u32x4*)(rowbm + ((jb + 128) >> 5));
#pragma unroll
    for (int st = 0; st < 4; ++st) {
      const int jq = jb + st * 32;           // 32-j chunk base
      const int jc = jq >> 5;
      const h16x8 bx0 = *(const h16x8*)(xb + (size_t)jc * 1024);
      const h16x8 bx1 = *(const h16x8*)(xb + (size_t)jc * 1024 + 512);
      const h16x8 e1 = *(const h16x8*)(E1 + jq + qd * 8);
      const h16x8 e2 = *(const h16x8*)(E2 + jq + qd * 8);

      union { h16x8 h; uint32_t u[4]; s16x2 s2[4]; } A, B, P;
      A.h = F1 * e1;                         // p if v >= 0
      B.h = F2 * e2;                         // p if v <  0

      const uint32_t t8 = (bits[st] >> (qd * 8)) & 0xFFu;
      const uint32_t r8 = t8 | (t8 << 16);
#pragma unroll
      for (int k = 0; k < 4; ++k) {
        // v>=0  <=>  a>=1.0  <=>  bits(a) >= 0x3C00 (positive f16s)
        const s16x2 d = A.s2[k] - (s16x2){0x3C00, 0x3C00};
        union { s16x2 s; uint32_t u; } M;
        M.s = d >> (s16x2){15, 15};          // 0xFFFF where a<1 -> pick b
        const uint32_t sel = A.u[k] ^ ((A.u[k] ^ B.u[k]) & M.u);
        union { uint32_t u; s16x2 s; } adjm;
        adjm.u = r8;
        adjm.s = adjm.s << (s16x2){(short)(15 - 2 * k), (short)(14 - 2 * k)};
        adjm.s = adjm.s >> (s16x2){15, 15};  // 0xFFFF where edge present
        P.u[k] = sel & adjm.u;
      }

      acc0 = __builtin_amdgcn_mfma_f32_16x16x32_f16(P.h, bx0, acc0, 0, 0, 0);
      acc1 = __builtin_amdgcn_mfma_f32_16x16x32_f16(P.h, bx1, acc1, 0, 0, 0);
      accD = __builtin_amdgcn_mfma_f32_16x16x32_f16(P.h, ONES, accD, 0, 0, 0);
    }
    bits = nbits;
  }

  // cross-wave reduction: waves 1..3 dump, wave 0 sums + writes out
  if (wv > 0) {
#pragma unroll
    for (int r = 0; r < 4; ++r) {
      Red[wv - 1][ln][r] = acc0[r];
      Red[wv - 1][ln][4 + r] = acc1[r];
      Red[wv - 1][ln][8 + r] = accD[r];
    }
  }
  __syncthreads();
  if (wv == 0) {
#pragma unroll
    for (int w = 0; w < 3; ++w)
#pragma unroll
      for (int r = 0; r < 4; ++r) {
        acc0[r] += Red[w][ln][r];
        acc1[r] += Red[w][ln][4 + r];
        accD[r] += Red[w][ln][8 + r];
      }
#pragma unroll
    for (int r = 0; r < 4; ++r) {
      const int rw = qd * 4 + r;
      const float inv = 1.0f / accD[r];
      out[(size_t)(i0 + rw) * HF + h * 32 + nl] = acc0[r] * inv;
      out[(size_t)(i0 + rw) * HF + h * 32 + 16 + nl] = acc1[r] * inv;
    }
  }
}

// ---------------------------------------------------------------------------
extern "C" void kernel_launch(void* const* d_in, const int* in_sizes, int n_in,
                              void* d_out, int out_size, void* d_ws, size_t ws_size,
                              hipStream_t stream) {
  const float* node = (const float*)d_in[0];
  const void* adj = d_in[1];
  const float* Wm = (const float*)d_in[2];
  const float* avec = (const float*)d_in[3];
  float* out = (float*)d_out;

  uint8_t* ws = (uint8_t*)d_ws;
  _Float16* XB = (_Float16*)ws;                        // 2 MB (frag-major X)
  _Float16* srcE1 = (_Float16*)(ws + 0x200000);        // 64 KB each
  _Float16* srcE2 = (_Float16*)(ws + 0x210000);
  _Float16* tgtF1 = (_Float16*)(ws + 0x220000);
  _Float16* tgtF2 = (_Float16*)(ws + 0x230000);
  uint32_t* bm = (uint32_t*)(ws + 0x240000);           // 2 MB bitmask

  hipLaunchKernelGGL(k_pre, dim3(2304), dim3(256), 0, stream,
                     adj, node, Wm, avec, bm, XB, srcE1, srcE2, tgtF1, tgtF2);
  hipLaunchKernelGGL(k_attn, dim3(2048), dim3(256), 0, stream,
                     bm, XB, srcE1, srcE2, tgtF1, tgtF2, out);
}

// Round 11
// 159.074 us; speedup vs baseline: 1.1419x; 1.1419x over previous
//
#include <hip/hip_runtime.h>
#include <hip/hip_bf16.h>
#include <stdint.h>

#define NN 4096
#define KIN 512
#define HH 8
#define HF 256
#define LOG2E 1.4426950408889634f

typedef float f32x4 __attribute__((ext_vector_type(4)));
typedef short s16x8 __attribute__((ext_vector_type(8)));
typedef short s16x2 __attribute__((ext_vector_type(2)));
typedef __bf16 bf16x8 __attribute__((ext_vector_type(8)));
typedef _Float16 h16x8 __attribute__((ext_vector_type(8)));
typedef unsigned int u32x4 __attribute__((ext_vector_type(4)));

// ---------------------------------------------------------------------------
// k_pre: fused prep (blocks 0..255) + pack (blocks 256..2303).
//  prep: x = node@W via bf16 MFMA; emits XB (f16, B-fragment-major, 2 MB)
//        and f16 score tables E1=2^s, E2=2^(0.2s), F1=2^t, F2=2^(0.2t).
//  pack: adjacency -> bitmask bm[4096][128] u32 (2 MB). Coalesced 1KB wave
//        loads (lane-stride 16B), bit assembly via shuffle-OR butterfly,
//        4 chunks in flight per iteration for MLP.
// ---------------------------------------------------------------------------
__global__ __launch_bounds__(256) void k_pre(
    const void* __restrict__ adjv, const float* __restrict__ node,
    const float* __restrict__ Wm, const float* __restrict__ avec,
    uint32_t* __restrict__ bm, _Float16* __restrict__ XB,
    _Float16* __restrict__ srcE1, _Float16* __restrict__ srcE2,
    _Float16* __restrict__ tgtF1, _Float16* __restrict__ tgtF2) {
  __shared__ __bf16 Ald[64][40];
  __shared__ __bf16 Bld[64][40];
  __shared__ _Float16 Cs[64][72];
  const int tid = threadIdx.x;
  const int wv = tid >> 6, ln = tid & 63;

  if (blockIdx.x >= 256) {
    // ---------------- pack path ----------------
    __shared__ int smode;
    if (tid == 0) {
      const uint32_t* aw = (const uint32_t*)adjv;
      const uint32_t w0 = aw[0];
      int f;
      if (w0 == 0x3F800000u) f = 2;               // fp32 0/1
      else if ((w0 & 0xFFFFu) == 0x3F80u) f = 3;  // bf16 0/1
      else {
        int alli = 1;
        for (int k = 0; k < 64; ++k)
          if (aw[k] > 1u) { alli = 0; break; }
        f = alli ? 1 : 0;                         // int32 : uint8
      }
      smode = f;
    }
    __syncthreads();
    const int mode = smode;
    const int pw = (blockIdx.x - 256) * 4 + wv;   // 0..8191
    const int NPW = (gridDim.x - 256) * 4;        // 8192
    const uint8_t* src = (const uint8_t*)adjv;
    const int esz = (mode == 0) ? 1 : ((mode == 3) ? 2 : 4);
    const int totalIters = (NN / 64) * (NN / 64) * esz;  // bytes>>12

    for (int it = pw; it < totalIters; it += NPW) {
      // 4 x 1KB coalesced chunk loads, all issued before decode
      const u32x4* p = (const u32x4*)(src + (size_t)it * 4096) + ln;
      u32x4 v[4];
#pragma unroll
      for (int c = 0; c < 4; ++c)
        v[c] = __builtin_nontemporal_load(p + c * 64);

#pragma unroll
      for (int c = 0; c < 4; ++c) {
        uint32_t b = 0;
        if (mode == 0) {
          // 16 elems/lane -> 16 bits at (ln&1)*16; word from 2 lanes
#pragma unroll
          for (int q = 0; q < 4; ++q)
#pragma unroll
            for (int bb = 0; bb < 4; ++bb)
              if ((v[c][q] >> (8 * bb)) & 0xFFu) b |= (1u << (q * 4 + bb));
          b <<= (ln & 1) * 16;
          b |= __shfl_xor(b, 1);
          if ((ln & 1) == 0) bm[it * 128 + c * 32 + (ln >> 1)] = b;
        } else if (mode == 3) {
          // 8 elems/lane -> 8 bits at (ln&3)*8; word from 4 lanes
#pragma unroll
          for (int q = 0; q < 4; ++q) {
            if (v[c][q] & 0xFFFFu) b |= (1u << (q * 2));
            if (v[c][q] >> 16)     b |= (1u << (q * 2 + 1));
          }
          b <<= (ln & 3) * 8;
          b |= __shfl_xor(b, 1);
          b |= __shfl_xor(b, 2);
          if ((ln & 3) == 0) bm[it * 64 + c * 16 + (ln >> 2)] = b;
        } else {
          // 4 elems/lane -> 4 bits at (ln&7)*4; word from 8 lanes
#pragma unroll
          for (int q = 0; q < 4; ++q)
            if (v[c][q]) b |= (1u << q);
          b <<= (ln & 7) * 4;
          b |= __shfl_xor(b, 1);
          b |= __shfl_xor(b, 2);
          b |= __shfl_xor(b, 4);
          if ((ln & 7) == 0) bm[it * 32 + c * 8 + (ln >> 3)] = b;
        }
      }
    }
    return;
  }

  // ---------------- prep path (blocks 0..255) ----------------
  const int pb = blockIdx.x;                      // 0..255
  const int bx = pb & 63, by = pb >> 6;
  const int nl = ln & 15, qd = ln >> 4;
  const int row0 = bx * 64, col0 = by * 64;
  const int rA = tid >> 2, kA = (tid & 3) * 8;
  const int kB = tid >> 3, cB = (tid & 7) * 8;

  f32x4 acc[4] = {{0,0,0,0},{0,0,0,0},{0,0,0,0},{0,0,0,0}};
  float4 a0, a1, b0, b1;

  auto ldg = [&](int k0) {
    a0 = *(const float4*)(node + (size_t)(row0 + rA) * KIN + k0 + kA);
    a1 = *(const float4*)(node + (size_t)(row0 + rA) * KIN + k0 + kA + 4);
    b0 = *(const float4*)(Wm + (size_t)(k0 + kB) * HF + col0 + cB);
    b1 = *(const float4*)(Wm + (size_t)(k0 + kB) * HF + col0 + cB + 4);
  };

  ldg(0);
  for (int k0 = 0; k0 < KIN; k0 += 32) {
    __syncthreads();
    {
      union { bf16x8 v; s16x8 s; } pk;
      pk.v[0] = (__bf16)a0.x; pk.v[1] = (__bf16)a0.y;
      pk.v[2] = (__bf16)a0.z; pk.v[3] = (__bf16)a0.w;
      pk.v[4] = (__bf16)a1.x; pk.v[5] = (__bf16)a1.y;
      pk.v[6] = (__bf16)a1.z; pk.v[7] = (__bf16)a1.w;
      *(s16x8*)&Ald[rA][kA] = pk.s;
      Bld[cB + 0][kB] = (__bf16)b0.x;
      Bld[cB + 1][kB] = (__bf16)b0.y;
      Bld[cB + 2][kB] = (__bf16)b0.z;
      Bld[cB + 3][kB] = (__bf16)b0.w;
      Bld[cB + 4][kB] = (__bf16)b1.x;
      Bld[cB + 5][kB] = (__bf16)b1.y;
      Bld[cB + 6][kB] = (__bf16)b1.z;
      Bld[cB + 7][kB] = (__bf16)b1.w;
    }
    __syncthreads();
    if (k0 + 32 < KIN) ldg(k0 + 32);
    const s16x8 af = *(const s16x8*)&Ald[wv * 16 + nl][qd * 8];
#pragma unroll
    for (int ct = 0; ct < 4; ++ct) {
      const s16x8 bfr = *(const s16x8*)&Bld[ct * 16 + nl][qd * 8];
      acc[ct] = __builtin_amdgcn_mfma_f32_16x16x32_bf16(af, bfr, acc[ct], 0, 0, 0);
    }
  }

  // stage C-tile in LDS [col][row] as f16
#pragma unroll
  for (int ct = 0; ct < 4; ++ct)
#pragma unroll
    for (int r = 0; r < 4; ++r)
      Cs[ct * 16 + nl][wv * 16 + qd * 4 + r] = (_Float16)acc[ct][r];
  __syncthreads();
  // write XB: 8 combos (hp, jcl, half) x 64 lanes, 16B each, coalesced
  {
    const int l = tid & 63;
#pragma unroll
    for (int i = 0; i < 2; ++i) {
      const int cmb = i * 4 + (tid >> 6);
      const int hp = cmb >> 2, jcl = (cmb >> 1) & 1, half = cmb & 1;
      const int cp = hp * 32 + half * 16 + (l & 15);
      const int rp = jcl * 32 + (l >> 4) * 8;
      const int hg = by * 2 + hp;
      const int jc = bx * 2 + jcl;
      *(h16x8*)(XB + (((size_t)(hg * 128 + jc)) * 2 + half) * 512 + l * 8) =
          *(const h16x8*)&Cs[cp][rp];
    }
  }

  const float as0 = avec[nl] * LOG2E, as1 = avec[16 + nl] * LOG2E;
  const float at0 = avec[32 + nl] * LOG2E, at1 = avec[48 + nl] * LOG2E;
#pragma unroll
  for (int hp = 0; hp < 2; ++hp) {
    float ps[4], pt[4];
#pragma unroll
    for (int r = 0; r < 4; ++r) {
      ps[r] = acc[2 * hp][r] * as0 + acc[2 * hp + 1][r] * as1;
      pt[r] = acc[2 * hp][r] * at0 + acc[2 * hp + 1][r] * at1;
    }
#pragma unroll
    for (int m = 1; m <= 8; m <<= 1)
#pragma unroll
      for (int r = 0; r < 4; ++r) {
        ps[r] += __shfl_xor(ps[r], m);
        pt[r] += __shfl_xor(pt[r], m);
      }
    if (nl == 0) {
      const int h = by * 2 + hp;
#pragma unroll
      for (int r = 0; r < 4; ++r) {
        const int idx = h * NN + row0 + wv * 16 + qd * 4 + r;
        srcE1[idx] = (_Float16)exp2f(ps[r]);
        srcE2[idx] = (_Float16)exp2f(0.2f * ps[r]);
        tgtF1[idx] = (_Float16)exp2f(pt[r]);
        tgtF2[idx] = (_Float16)exp2f(0.2f * pt[r]);
      }
    }
  }
}

// ---------------------------------------------------------------------------
// k_attn: block = (16-row tile, head), 4 waves each owning a 1024-j slice.
// No transcendentals: p = adj & (a>=1 ? a : b), a=F1*E1, b=F2*E2 (packed
// f16 muls; branch select via integer compare on positive-f16 bit patterns).
// f16 MFMA (f32 accum); den via ones-MFMA; cross-wave LDS reduction.
// ---------------------------------------------------------------------------
__global__ __launch_bounds__(256, 8) void k_attn(
    const uint32_t* __restrict__ bm, const _Float16* __restrict__ XB,
    const _Float16* __restrict__ srcE1, const _Float16* __restrict__ srcE2,
    const _Float16* __restrict__ tgtF1, const _Float16* __restrict__ tgtF2,
    float* __restrict__ out) {
  __shared__ float Red[3][64][13];
  const int tid = threadIdx.x;
  const int wv = tid >> 6, ln = tid & 63, nl = ln & 15, qd = ln >> 4;
  const int tile = blockIdx.x >> 3;          // 0..255
  const int h = blockIdx.x & 7;
  const int i0 = tile * 16;
  const int j0 = wv * 1024;

  const _Float16 f1 = tgtF1[h * NN + i0 + nl];
  const _Float16 f2 = tgtF2[h * NN + i0 + nl];
  const h16x8 F1 = {f1, f1, f1, f1, f1, f1, f1, f1};
  const h16x8 F2 = {f2, f2, f2, f2, f2, f2, f2, f2};
  const h16x8 ONES = {(_Float16)1.0f, (_Float16)1.0f, (_Float16)1.0f,
                      (_Float16)1.0f, (_Float16)1.0f, (_Float16)1.0f,
                      (_Float16)1.0f, (_Float16)1.0f};
  const _Float16* E1 = srcE1 + h * NN;
  const _Float16* E2 = srcE2 + h * NN;
  const _Float16* xb = XB + ((size_t)h << 17) + ln * 8;
  const uint32_t* rowbm = bm + (size_t)(i0 + nl) * 128;

  f32x4 acc0 = {0,0,0,0}, acc1 = {0,0,0,0}, accD = {0,0,0,0};

  u32x4 bits = *(const u32x4*)(rowbm + (j0 >> 5));
  for (int c = 0; c < 8; ++c) {
    const int jb = j0 + c * 128;
    u32x4 nbits;
    if (c + 1 < 8) nbits = *(const u32x4*)(rowbm + ((jb + 128) >> 5));
#pragma unroll
    for (int st = 0; st < 4; ++st) {
      const int jq = jb + st * 32;           // 32-j chunk base
      const int jc = jq >> 5;
      const h16x8 bx0 = *(const h16x8*)(xb + (size_t)jc * 1024);
      const h16x8 bx1 = *(const h16x8*)(xb + (size_t)jc * 1024 + 512);
      const h16x8 e1 = *(const h16x8*)(E1 + jq + qd * 8);
      const h16x8 e2 = *(const h16x8*)(E2 + jq + qd * 8);

      union { h16x8 h; uint32_t u[4]; s16x2 s2[4]; } A, B, P;
      A.h = F1 * e1;                         // p if v >= 0
      B.h = F2 * e2;                         // p if v <  0

      const uint32_t t8 = (bits[st] >> (qd * 8)) & 0xFFu;
      const uint32_t r8 = t8 | (t8 << 16);
#pragma unroll
      for (int k = 0; k < 4; ++k) {
        // v>=0  <=>  a>=1.0  <=>  bits(a) >= 0x3C00 (positive f16s)
        const s16x2 d = A.s2[k] - (s16x2){0x3C00, 0x3C00};
        union { s16x2 s; uint32_t u; } M;
        M.s = d >> (s16x2){15, 15};          // 0xFFFF where a<1 -> pick b
        const uint32_t sel = A.u[k] ^ ((A.u[k] ^ B.u[k]) & M.u);
        union { uint32_t u; s16x2 s; } adjm;
        adjm.u = r8;
        adjm.s = adjm.s << (s16x2){(short)(15 - 2 * k), (short)(14 - 2 * k)};
        adjm.s = adjm.s >> (s16x2){15, 15};  // 0xFFFF where edge present
        P.u[k] = sel & adjm.u;
      }

      acc0 = __builtin_amdgcn_mfma_f32_16x16x32_f16(P.h, bx0, acc0, 0, 0, 0);
      acc1 = __builtin_amdgcn_mfma_f32_16x16x32_f16(P.h, bx1, acc1, 0, 0, 0);
      accD = __builtin_amdgcn_mfma_f32_16x16x32_f16(P.h, ONES, accD, 0, 0, 0);
    }
    bits = nbits;
  }

  // cross-wave reduction: waves 1..3 dump, wave 0 sums + writes out
  if (wv > 0) {
#pragma unroll
    for (int r = 0; r < 4; ++r) {
      Red[wv - 1][ln][r] = acc0[r];
      Red[wv - 1][ln][4 + r] = acc1[r];
      Red[wv - 1][ln][8 + r] = accD[r];
    }
  }
  __syncthreads();
  if (wv == 0) {
#pragma unroll
    for (int w = 0; w < 3; ++w)
#pragma unroll
      for (int r = 0; r < 4; ++r) {
        acc0[r] += Red[w][ln][r];
        acc1[r] += Red[w][ln][4 + r];
        accD[r] += Red[w][ln][8 + r];
      }
#pragma unroll
    for (int r = 0; r < 4; ++r) {
      const int rw = qd * 4 + r;
      const float inv = 1.0f / accD[r];
      out[(size_t)(i0 + rw) * HF + h * 32 + nl] = acc0[r] * inv;
      out[(size_t)(i0 + rw) * HF + h * 32 + 16 + nl] = acc1[r] * inv;
    }
  }
}

// ---------------------------------------------------------------------------
extern "C" void kernel_launch(void* const* d_in, const int* in_sizes, int n_in,
                              void* d_out, int out_size, void* d_ws, size_t ws_size,
                              hipStream_t stream) {
  const float* node = (const float*)d_in[0];
  const void* adj = d_in[1];
  const float* Wm = (const float*)d_in[2];
  const float* avec = (const float*)d_in[3];
  float* out = (float*)d_out;

  uint8_t* ws = (uint8_t*)d_ws;
  _Float16* XB = (_Float16*)ws;                        // 2 MB (frag-major X)
  _Float16* srcE1 = (_Float16*)(ws + 0x200000);        // 64 KB each
  _Float16* srcE2 = (_Float16*)(ws + 0x210000);
  _Float16* tgtF1 = (_Float16*)(ws + 0x220000);
  _Float16* tgtF2 = (_Float16*)(ws + 0x230000);
  uint32_t* bm = (uint32_t*)(ws + 0x240000);           // 2 MB bitmask

  hipLaunchKernelGGL(k_pre, dim3(2304), dim3(256), 0, stream,
                     adj, node, Wm, avec, bm, XB, srcE1, srcE2, tgtF1, tgtF2);
  hipLaunchKernelGGL(k_attn, dim3(2048), dim3(256), 0, stream,
                     bm, XB, srcE1, srcE2, tgtF1, tgtF2, out);
}

// Round 12
// 144.320 us; speedup vs baseline: 1.2586x; 1.1022x over previous
//
#include <hip/hip_runtime.h>
#include <hip/hip_bf16.h>
#include <stdint.h>

#define NN 4096
#define KIN 512
#define HH 8
#define HF 256
#define LOG2E 1.4426950408889634f

typedef float f32x4 __attribute__((ext_vector_type(4)));
typedef short s16x8 __attribute__((ext_vector_type(8)));
typedef short s16x2 __attribute__((ext_vector_type(2)));
typedef __bf16 bf16x8 __attribute__((ext_vector_type(8)));
typedef _Float16 h16x8 __attribute__((ext_vector_type(8)));
typedef unsigned int u32x4 __attribute__((ext_vector_type(4)));

// ---------------------------------------------------------------------------
// k_pre: fused prep (blocks 0..255) + pack (blocks 256..2303).
//  prep: x = node@W via bf16 MFMA; emits XB (f16, B-fragment-major, 2 MB)
//        and f16 score tables E1=2^s, E2=2^(0.2s), F1=2^t, F2=2^(0.2t).
//  pack: adjacency -> bitmask bm[4096][128] u32 (2 MB). Coalesced 1KB wave
//        loads, bit assembly via shuffle-OR butterfly, 4 chunks in flight.
// ---------------------------------------------------------------------------
__global__ __launch_bounds__(256) void k_pre(
    const void* __restrict__ adjv, const float* __restrict__ node,
    const float* __restrict__ Wm, const float* __restrict__ avec,
    uint32_t* __restrict__ bm, _Float16* __restrict__ XB,
    _Float16* __restrict__ srcE1, _Float16* __restrict__ srcE2,
    _Float16* __restrict__ tgtF1, _Float16* __restrict__ tgtF2) {
  __shared__ __bf16 Ald[64][40];
  __shared__ __bf16 Bld[64][40];
  __shared__ _Float16 Cs[64][72];
  const int tid = threadIdx.x;
  const int wv = tid >> 6, ln = tid & 63;

  if (blockIdx.x >= 256) {
    // ---------------- pack path ----------------
    __shared__ int smode;
    if (tid == 0) {
      const uint32_t* aw = (const uint32_t*)adjv;
      const uint32_t w0 = aw[0];
      int f;
      if (w0 == 0x3F800000u) f = 2;               // fp32 0/1
      else if ((w0 & 0xFFFFu) == 0x3F80u) f = 3;  // bf16 0/1
      else {
        int alli = 1;
        for (int k = 0; k < 64; ++k)
          if (aw[k] > 1u) { alli = 0; break; }
        f = alli ? 1 : 0;                         // int32 : uint8
      }
      smode = f;
    }
    __syncthreads();
    const int mode = smode;
    const int pw = (blockIdx.x - 256) * 4 + wv;   // 0..8191
    const int NPW = (gridDim.x - 256) * 4;        // 8192
    const uint8_t* src = (const uint8_t*)adjv;
    const int esz = (mode == 0) ? 1 : ((mode == 3) ? 2 : 4);
    const int totalIters = (NN / 64) * (NN / 64) * esz;  // bytes>>12

    for (int it = pw; it < totalIters; it += NPW) {
      const u32x4* p = (const u32x4*)(src + (size_t)it * 4096) + ln;
      u32x4 v[4];
#pragma unroll
      for (int c = 0; c < 4; ++c)
        v[c] = __builtin_nontemporal_load(p + c * 64);

#pragma unroll
      for (int c = 0; c < 4; ++c) {
        uint32_t b = 0;
        if (mode == 0) {
#pragma unroll
          for (int q = 0; q < 4; ++q)
#pragma unroll
            for (int bb = 0; bb < 4; ++bb)
              if ((v[c][q] >> (8 * bb)) & 0xFFu) b |= (1u << (q * 4 + bb));
          b <<= (ln & 1) * 16;
          b |= __shfl_xor(b, 1);
          if ((ln & 1) == 0) bm[it * 128 + c * 32 + (ln >> 1)] = b;
        } else if (mode == 3) {
#pragma unroll
          for (int q = 0; q < 4; ++q) {
            if (v[c][q] & 0xFFFFu) b |= (1u << (q * 2));
            if (v[c][q] >> 16)     b |= (1u << (q * 2 + 1));
          }
          b <<= (ln & 3) * 8;
          b |= __shfl_xor(b, 1);
          b |= __shfl_xor(b, 2);
          if ((ln & 3) == 0) bm[it * 64 + c * 16 + (ln >> 2)] = b;
        } else {
#pragma unroll
          for (int q = 0; q < 4; ++q)
            if (v[c][q]) b |= (1u << q);
          b <<= (ln & 7) * 4;
          b |= __shfl_xor(b, 1);
          b |= __shfl_xor(b, 2);
          b |= __shfl_xor(b, 4);
          if ((ln & 7) == 0) bm[it * 32 + c * 8 + (ln >> 3)] = b;
        }
      }
    }
    return;
  }

  // ---------------- prep path (blocks 0..255) ----------------
  const int pb = blockIdx.x;                      // 0..255
  const int bx = pb & 63, by = pb >> 6;
  const int nl = ln & 15, qd = ln >> 4;
  const int row0 = bx * 64, col0 = by * 64;
  const int rA = tid >> 2, kA = (tid & 3) * 8;
  const int kB = tid >> 3, cB = (tid & 7) * 8;

  f32x4 acc[4] = {{0,0,0,0},{0,0,0,0},{0,0,0,0},{0,0,0,0}};
  float4 a0, a1, b0, b1;

  auto ldg = [&](int k0) {
    a0 = *(const float4*)(node + (size_t)(row0 + rA) * KIN + k0 + kA);
    a1 = *(const float4*)(node + (size_t)(row0 + rA) * KIN + k0 + kA + 4);
    b0 = *(const float4*)(Wm + (size_t)(k0 + kB) * HF + col0 + cB);
    b1 = *(const float4*)(Wm + (size_t)(k0 + kB) * HF + col0 + cB + 4);
  };

  ldg(0);
  for (int k0 = 0; k0 < KIN; k0 += 32) {
    __syncthreads();
    {
      union { bf16x8 v; s16x8 s; } pk;
      pk.v[0] = (__bf16)a0.x; pk.v[1] = (__bf16)a0.y;
      pk.v[2] = (__bf16)a0.z; pk.v[3] = (__bf16)a0.w;
      pk.v[4] = (__bf16)a1.x; pk.v[5] = (__bf16)a1.y;
      pk.v[6] = (__bf16)a1.z; pk.v[7] = (__bf16)a1.w;
      *(s16x8*)&Ald[rA][kA] = pk.s;
      Bld[cB + 0][kB] = (__bf16)b0.x;
      Bld[cB + 1][kB] = (__bf16)b0.y;
      Bld[cB + 2][kB] = (__bf16)b0.z;
      Bld[cB + 3][kB] = (__bf16)b0.w;
      Bld[cB + 4][kB] = (__bf16)b1.x;
      Bld[cB + 5][kB] = (__bf16)b1.y;
      Bld[cB + 6][kB] = (__bf16)b1.z;
      Bld[cB + 7][kB] = (__bf16)b1.w;
    }
    __syncthreads();
    if (k0 + 32 < KIN) ldg(k0 + 32);
    const s16x8 af = *(const s16x8*)&Ald[wv * 16 + nl][qd * 8];
#pragma unroll
    for (int ct = 0; ct < 4; ++ct) {
      const s16x8 bfr = *(const s16x8*)&Bld[ct * 16 + nl][qd * 8];
      acc[ct] = __builtin_amdgcn_mfma_f32_16x16x32_bf16(af, bfr, acc[ct], 0, 0, 0);
    }
  }

  // stage C-tile in LDS [col][row] as f16
#pragma unroll
  for (int ct = 0; ct < 4; ++ct)
#pragma unroll
    for (int r = 0; r < 4; ++r)
      Cs[ct * 16 + nl][wv * 16 + qd * 4 + r] = (_Float16)acc[ct][r];
  __syncthreads();
  // write XB: 8 combos (hp, jcl, half) x 64 lanes, 16B each, coalesced
  {
    const int l = tid & 63;
#pragma unroll
    for (int i = 0; i < 2; ++i) {
      const int cmb = i * 4 + (tid >> 6);
      const int hp = cmb >> 2, jcl = (cmb >> 1) & 1, half = cmb & 1;
      const int cp = hp * 32 + half * 16 + (l & 15);
      const int rp = jcl * 32 + (l >> 4) * 8;
      const int hg = by * 2 + hp;
      const int jc = bx * 2 + jcl;
      *(h16x8*)(XB + (((size_t)(hg * 128 + jc)) * 2 + half) * 512 + l * 8) =
          *(const h16x8*)&Cs[cp][rp];
    }
  }

  const float as0 = avec[nl] * LOG2E, as1 = avec[16 + nl] * LOG2E;
  const float at0 = avec[32 + nl] * LOG2E, at1 = avec[48 + nl] * LOG2E;
#pragma unroll
  for (int hp = 0; hp < 2; ++hp) {
    float ps[4], pt[4];
#pragma unroll
    for (int r = 0; r < 4; ++r) {
      ps[r] = acc[2 * hp][r] * as0 + acc[2 * hp + 1][r] * as1;
      pt[r] = acc[2 * hp][r] * at0 + acc[2 * hp + 1][r] * at1;
    }
#pragma unroll
    for (int m = 1; m <= 8; m <<= 1)
#pragma unroll
      for (int r = 0; r < 4; ++r) {
        ps[r] += __shfl_xor(ps[r], m);
        pt[r] += __shfl_xor(pt[r], m);
      }
    if (nl == 0) {
      const int h = by * 2 + hp;
#pragma unroll
      for (int r = 0; r < 4; ++r) {
        const int idx = h * NN + row0 + wv * 16 + qd * 4 + r;
        srcE1[idx] = (_Float16)exp2f(ps[r]);
        srcE2[idx] = (_Float16)exp2f(0.2f * ps[r]);
        tgtF1[idx] = (_Float16)exp2f(pt[r]);
        tgtF2[idx] = (_Float16)exp2f(0.2f * pt[r]);
      }
    }
  }
}

// ---------------------------------------------------------------------------
// k_attn: block = (32-row tile-pair, head), 8 waves each owning a 512-j
// slice; each wave computes TWO 16-row tiles sharing the same XB/E loads
// (2x vmem amortization). Score: p = adj & max(F1*E1, F2*E2) — leaky-relu
// in exp2 domain IS elementwise max (exp2 monotone). f16 MFMA, f32 accum,
// den via ones-MFMA. LDS tree reduction across the 8 j-slices.
// ---------------------------------------------------------------------------
__global__ __launch_bounds__(512) void k_attn(
    const uint32_t* __restrict__ bm, const _Float16* __restrict__ XB,
    const _Float16* __restrict__ srcE1, const _Float16* __restrict__ srcE2,
    const _Float16* __restrict__ tgtF1, const _Float16* __restrict__ tgtF2,
    float* __restrict__ out) {
  __shared__ float Red[4][64][25];  // tree buffer; stride 25: conflict-free
  const int tid = threadIdx.x;
  const int wv = tid >> 6, ln = tid & 63, nl = ln & 15, qd = ln >> 4;
  const int tp = blockIdx.x >> 3;            // tile-pair 0..127
  const int h = blockIdx.x & 7;
  const int i0 = tp * 32;
  const int j0 = wv * 512;

  const int rb = h * NN + i0 + nl;
  const _Float16 f1a = tgtF1[rb],      f2a = tgtF2[rb];
  const _Float16 f1b = tgtF1[rb + 16], f2b = tgtF2[rb + 16];
  const h16x8 F1a = {f1a, f1a, f1a, f1a, f1a, f1a, f1a, f1a};
  const h16x8 F2a = {f2a, f2a, f2a, f2a, f2a, f2a, f2a, f2a};
  const h16x8 F1b = {f1b, f1b, f1b, f1b, f1b, f1b, f1b, f1b};
  const h16x8 F2b = {f2b, f2b, f2b, f2b, f2b, f2b, f2b, f2b};
  const h16x8 ONES = {(_Float16)1.0f, (_Float16)1.0f, (_Float16)1.0f,
                      (_Float16)1.0f, (_Float16)1.0f, (_Float16)1.0f,
                      (_Float16)1.0f, (_Float16)1.0f};
  const _Float16* E1 = srcE1 + h * NN;
  const _Float16* E2 = srcE2 + h * NN;
  const _Float16* xb = XB + ((size_t)h << 17) + ln * 8;
  const uint32_t* rbmA = bm + (size_t)(i0 + nl) * 128;
  const uint32_t* rbmB = rbmA + 16 * 128;

  // acc[0..2] = tile a (num0, num1, den); acc[3..5] = tile b
  f32x4 acc[6] = {{0,0,0,0},{0,0,0,0},{0,0,0,0},{0,0,0,0},{0,0,0,0},{0,0,0,0}};

  auto mkP = [&](const h16x8& A1, const h16x8& A2, uint32_t bw) -> h16x8 {
    union { h16x8 h; uint32_t u[4]; } P;
    P.h = __builtin_elementwise_max(A1, A2);
    const uint32_t r8 = bw | (bw << 16);
#pragma unroll
    for (int k = 0; k < 4; ++k) {
      union { uint32_t u; s16x2 s; } m;
      m.u = r8;
      m.s = m.s << (s16x2){(short)(15 - 2 * k), (short)(14 - 2 * k)};
      m.s = m.s >> (s16x2){15, 15};          // 0xFFFF where edge present
      P.u[k] &= m.u;
    }
    return P.h;
  };

  u32x4 bitsA = *(const u32x4*)(rbmA + (j0 >> 5));
  u32x4 bitsB = *(const u32x4*)(rbmB + (j0 >> 5));
  for (int c = 0; c < 4; ++c) {
    const int jb = j0 + c * 128;
    u32x4 nbitsA, nbitsB;
    if (c + 1 < 4) {
      nbitsA = *(const u32x4*)(rbmA + ((jb + 128) >> 5));
      nbitsB = *(const u32x4*)(rbmB + ((jb + 128) >> 5));
    }
#pragma unroll
    for (int st = 0; st < 4; ++st) {
      const int jq = jb + st * 32;           // 32-j chunk base
      const int jc = jq >> 5;
      const h16x8 bx0 = *(const h16x8*)(xb + (size_t)jc * 1024);
      const h16x8 bx1 = *(const h16x8*)(xb + (size_t)jc * 1024 + 512);
      const h16x8 e1 = *(const h16x8*)(E1 + jq + qd * 8);
      const h16x8 e2 = *(const h16x8*)(E2 + jq + qd * 8);

      const uint32_t bwA = (bitsA[st] >> (qd * 8)) & 0xFFu;
      const uint32_t bwB = (bitsB[st] >> (qd * 8)) & 0xFFu;

      const h16x8 Pa = mkP(F1a * e1, F2a * e2, bwA);
      const h16x8 Pb = mkP(F1b * e1, F2b * e2, bwB);

      acc[0] = __builtin_amdgcn_mfma_f32_16x16x32_f16(Pa, bx0, acc[0], 0, 0, 0);
      acc[1] = __builtin_amdgcn_mfma_f32_16x16x32_f16(Pa, bx1, acc[1], 0, 0, 0);
      acc[2] = __builtin_amdgcn_mfma_f32_16x16x32_f16(Pa, ONES, acc[2], 0, 0, 0);
      acc[3] = __builtin_amdgcn_mfma_f32_16x16x32_f16(Pb, bx0, acc[3], 0, 0, 0);
      acc[4] = __builtin_amdgcn_mfma_f32_16x16x32_f16(Pb, bx1, acc[4], 0, 0, 0);
      acc[5] = __builtin_amdgcn_mfma_f32_16x16x32_f16(Pb, ONES, acc[5], 0, 0, 0);
    }
    bitsA = nbitsA;
    bitsB = nbitsB;
  }

  // tree reduction over 8 j-slices (3 rounds)
  auto dump = [&](int slot) {
#pragma unroll
    for (int t = 0; t < 6; ++t)
#pragma unroll
      for (int r = 0; r < 4; ++r) Red[slot][ln][t * 4 + r] = acc[t][r];
  };
  auto addin = [&](int slot) {
#pragma unroll
    for (int t = 0; t < 6; ++t)
#pragma unroll
      for (int r = 0; r < 4; ++r) acc[t][r] += Red[slot][ln][t * 4 + r];
  };
  if (wv >= 4) dump(wv - 4);
  __syncthreads();
  if (wv < 4) addin(wv);
  __syncthreads();
  if (wv == 2 || wv == 3) dump(wv - 2);
  __syncthreads();
  if (wv < 2) addin(wv);
  __syncthreads();
  if (wv == 1) dump(0);
  __syncthreads();
  if (wv == 0) {
    addin(0);
#pragma unroll
    for (int r = 0; r < 4; ++r) {
      const int rw = qd * 4 + r;
      const float ia = 1.0f / acc[2][r];
      out[(size_t)(i0 + rw) * HF + h * 32 + nl] = acc[0][r] * ia;
      out[(size_t)(i0 + rw) * HF + h * 32 + 16 + nl] = acc[1][r] * ia;
      const float ib = 1.0f / acc[5][r];
      out[(size_t)(i0 + 16 + rw) * HF + h * 32 + nl] = acc[3][r] * ib;
      out[(size_t)(i0 + 16 + rw) * HF + h * 32 + 16 + nl] = acc[4][r] * ib;
    }
  }
}

// ---------------------------------------------------------------------------
extern "C" void kernel_launch(void* const* d_in, const int* in_sizes, int n_in,
                              void* d_out, int out_size, void* d_ws, size_t ws_size,
                              hipStream_t stream) {
  const float* node = (const float*)d_in[0];
  const void* adj = d_in[1];
  const float* Wm = (const float*)d_in[2];
  const float* avec = (const float*)d_in[3];
  float* out = (float*)d_out;

  uint8_t* ws = (uint8_t*)d_ws;
  _Float16* XB = (_Float16*)ws;                        // 2 MB (frag-major X)
  _Float16* srcE1 = (_Float16*)(ws + 0x200000);        // 64 KB each
  _Float16* srcE2 = (_Float16*)(ws + 0x210000);
  _Float16* tgtF1 = (_Float16*)(ws + 0x220000);
  _Float16* tgtF2 = (_Float16*)(ws + 0x230000);
  uint32_t* bm = (uint32_t*)(ws + 0x240000);           // 2 MB bitmask

  hipLaunchKernelGGL(k_pre, dim3(2304), dim3(256), 0, stream,
                     adj, node, Wm, avec, bm, XB, srcE1, srcE2, tgtF1, tgtF2);
  hipLaunchKernelGGL(k_attn, dim3(1024), dim3(512), 0, stream,
                     bm, XB, srcE1, srcE2, tgtF1, tgtF2, out);
}